// Round 1
// 1375.608 us; speedup vs baseline: 1.1232x; 1.1232x over previous
//
#include <hip/hip_runtime.h>
#include <cstdint>

// Problem dims (fixed by reference): B=4, S=2048 -> M=8192, K=4096, N=16384
#define MDIM 8192
#define KDIM 4096
#define NDIM 16384

// GEMM geometry: 256x256 tile, 512 thr / 8 waves (2M x 4N), BK=64 bytes,
// 4-deep global_load_lds pipeline with counted vmcnt (T3+T4), T2 swizzle,
// T5 setprio, T1 XCD-chunked block swizzle.
#define BM 256
#define BN 256
#define BKB 64              // K-bytes per tile step (1 mfma k-step)
#define NT (KDIM / BKB)     // 64 K-tiles
#define NBUF 4

typedef int v4i __attribute__((ext_vector_type(4)));

__device__ __forceinline__ void gload_lds16(const void* g, void* l) {
    __builtin_amdgcn_global_load_lds(
        (const __attribute__((address_space(1))) int*)g,
        (__attribute__((address_space(3))) int*)l, 16, 0, 0);
}

// ---------------------------------------------------------------------------
// Kernel 1: pack W int32 [N,K] -> int8 [N,K]. One int4 (4 ints) -> one int (4 bytes).
__global__ __launch_bounds__(256) void conv_w(const int4* __restrict__ w,
                                              int* __restrict__ wq) {
    int g = blockIdx.x * 256 + threadIdx.x;   // int4 index; total N*K/4 = 16777216
    int4 v = w[g];
    unsigned p = (unsigned)(v.x & 255) | ((unsigned)(v.y & 255) << 8) |
                 ((unsigned)(v.z & 255) << 16) | ((unsigned)(v.w & 255) << 24);
    wq[g] = (int)p;
}

// ---------------------------------------------------------------------------
// Kernel 2: per-row absmax quantize of x [M,K] fp32 -> int8 + scale_x[M].
__global__ __launch_bounds__(256) void quant_rows(const float* __restrict__ x,
                                                  int* __restrict__ xq32,
                                                  float* __restrict__ sx) {
    const int row = blockIdx.x;
    const int t = threadIdx.x;
    const float4* xr = (const float4*)(x + (size_t)row * KDIM);

    float4 v[4];
    float amax = 0.f;
#pragma unroll
    for (int p = 0; p < 4; ++p) {
        v[p] = xr[p * 256 + t];
        amax = fmaxf(amax, fmaxf(fmaxf(fabsf(v[p].x), fabsf(v[p].y)),
                                 fmaxf(fabsf(v[p].z), fabsf(v[p].w))));
    }
#pragma unroll
    for (int off = 32; off > 0; off >>= 1)
        amax = fmaxf(amax, __shfl_down(amax, off));
    __shared__ float wmax[4];
    int wave = t >> 6, lane = t & 63;
    if (lane == 0) wmax[wave] = amax;
    __syncthreads();
    float m = fmaxf(fmaxf(wmax[0], wmax[1]), fmaxf(wmax[2], wmax[3]));

    float inv = (m > 0.f) ? 127.f / m : 0.f;
    if (t == 0) {
        float s = m / 127.f;
        sx[row] = (s == 0.f) ? 1.f : s;
    }

    int* out = xq32 + (size_t)row * (KDIM / 4);
#pragma unroll
    for (int p = 0; p < 4; ++p) {
        int q0 = (int)rintf(v[p].x * inv); q0 = max(-127, min(127, q0));
        int q1 = (int)rintf(v[p].y * inv); q1 = max(-127, min(127, q1));
        int q2 = (int)rintf(v[p].z * inv); q2 = max(-127, min(127, q2));
        int q3 = (int)rintf(v[p].w * inv); q3 = max(-127, min(127, q3));
        unsigned pk = (unsigned)(q0 & 255) | ((unsigned)(q1 & 255) << 8) |
                      ((unsigned)(q2 & 255) << 16) | ((unsigned)(q3 & 255) << 24);
        out[p * 256 + t] = (int)pk;
    }
}

// ---------------------------------------------------------------------------
// Kernel 3: int8 GEMM 256x256 tile, 8-phase-family schedule.
__global__ __launch_bounds__(512, 2) void gemm_i8(const signed char* __restrict__ xq,
                                                  const signed char* __restrict__ wq,
                                                  const float* __restrict__ sx,
                                                  const float* __restrict__ scale,
                                                  const float* __restrict__ bias,
                                                  float* __restrict__ y) {
    // 4 buffers x (A 16KB + B 16KB) = 128 KiB LDS -> 1 block/CU, 2 waves/SIMD
    __shared__ __align__(16) signed char lds_a[NBUF][BM * BKB];
    __shared__ __align__(16) signed char lds_b[NBUF][BN * BKB];

    const int tid  = threadIdx.x;
    const int lane = tid & 63;
    const int wave = tid >> 6;           // 0..7
    const int l16  = lane & 15;
    const int quad = lane >> 4;
    const int wm   = wave >> 2;          // 0..1  M-half
    const int wn   = wave & 3;           // 0..3  N-quarter

    // T1: bijective XCD-chunked swizzle (2048 blocks, 2048 % 8 == 0)
    int lin = blockIdx.y * gridDim.x + blockIdx.x;
    lin = (lin & 7) * ((MDIM / BM) * (NDIM / BN) / 8) + (lin >> 3);
    const int tileN = (lin & (NDIM / BN - 1)) * BN;   // lin % 64
    const int tileM = (lin >> 6) * BM;                // lin / 64

    // ---- staging addressing. T2 swizzle: LDS stays LINEAR for global_load_lds;
    // the global SOURCE column is pre-swizzled with the same involution the
    // ds_read side applies (rule 21: both-sides-or-neither).
    const int srow = tid >> 2;                                   // 0..127
    const int scol = ((tid & 3) << 4) ^ (((srow >> 1) & 3) << 4);
    const signed char* gA0 = xq + (size_t)(tileM + srow) * KDIM + scol;
    const signed char* gA1 = gA0 + (size_t)128 * KDIM;           // rows 128..255
    const signed char* gB0 = wq + (size_t)(tileN + srow) * KDIM + scol;
    const signed char* gB1 = gB0 + (size_t)128 * KDIM;
    const int lo = tid << 4;             // linear LDS byte offset of this thread's chunk

#define STAGE_A(t) do { const int _b = (t) & (NBUF - 1);                     \
        gload_lds16(gA0 + (size_t)(t) * BKB, &lds_a[_b][lo]);                \
        gload_lds16(gA1 + (size_t)(t) * BKB, &lds_a[_b][lo + 8192]); } while (0)
#define STAGE_B(t) do { const int _b = (t) & (NBUF - 1);                     \
        gload_lds16(gB0 + (size_t)(t) * BKB, &lds_b[_b][lo]);                \
        gload_lds16(gB1 + (size_t)(t) * BKB, &lds_b[_b][lo + 8192]); } while (0)

    // ---- ds_read addressing with the same XOR swizzle.
    // row = 16*a + l16 -> ((row>>1)&3) == ((l16>>1)&3): per-lane constant.
    const int rcol = (quad << 4) ^ (((l16 >> 1) & 3) << 4);
    const int aoff = (wm * 128 + l16) * BKB + rcol;   // + mf*1024
    const int boff = (wn * 64 + l16) * BKB + rcol;    // + nf*1024

    v4i acc[8][4] = {};

    // ---- prologue: tiles 0,1,2 in flight (12 loads); tile0 ready at vmcnt(8)
    STAGE_A(0); STAGE_B(0);
    STAGE_A(1); STAGE_B(1);
    STAGE_A(2); STAGE_B(2);
    asm volatile("s_waitcnt vmcnt(8)" ::: "memory");
    __builtin_amdgcn_s_barrier();

    for (int t = 0; t < NT; ++t) {
        const signed char* la = &lds_a[t & (NBUF - 1)][0];
        const signed char* lb = &lds_b[t & (NBUF - 1)][0];
        v4i af[4], bf[4], ag[4];

        // ---------- phase 1: M-half 0 ----------
#pragma unroll
        for (int i = 0; i < 4; ++i) af[i] = *(const v4i*)(la + aoff + i * 1024);
#pragma unroll
        for (int j = 0; j < 4; ++j) bf[j] = *(const v4i*)(lb + boff + j * 1024);
        if (t + 3 < NT) STAGE_A(t + 3);
        __builtin_amdgcn_s_barrier();
        asm volatile("s_waitcnt lgkmcnt(0)" ::: "memory");
        __builtin_amdgcn_sched_barrier(0);
        __builtin_amdgcn_s_setprio(1);
#pragma unroll
        for (int i = 0; i < 4; ++i)
#pragma unroll
            for (int j = 0; j < 4; ++j)
                acc[i][j] = __builtin_amdgcn_mfma_i32_16x16x64_i8(af[i], bf[j],
                                                                  acc[i][j], 0, 0, 0);
        __builtin_amdgcn_s_setprio(0);
        __builtin_amdgcn_s_barrier();

        // ---------- phase 2: M-half 1 ----------
#pragma unroll
        for (int i = 0; i < 4; ++i) ag[i] = *(const v4i*)(la + aoff + (4 + i) * 1024);
        if (t + 3 < NT) STAGE_B(t + 3);
        __builtin_amdgcn_s_barrier();
        asm volatile("s_waitcnt lgkmcnt(0)" ::: "memory");
        __builtin_amdgcn_sched_barrier(0);
        __builtin_amdgcn_s_setprio(1);
#pragma unroll
        for (int i = 0; i < 4; ++i)
#pragma unroll
            for (int j = 0; j < 4; ++j)
                acc[4 + i][j] = __builtin_amdgcn_mfma_i32_16x16x64_i8(ag[i], bf[j],
                                                                      acc[4 + i][j], 0, 0, 0);
        __builtin_amdgcn_s_setprio(0);
        // T4: counted vmcnt once per K-tile; never 0 in steady state.
        // Outstanding: tiles t+1,t+2,t+3 = 12 loads -> vmcnt(8) retires tile t+1.
        if (t <= NT - 4)      { asm volatile("s_waitcnt vmcnt(8)" ::: "memory"); }
        else if (t == NT - 3) { asm volatile("s_waitcnt vmcnt(4)" ::: "memory"); }
        else if (t == NT - 2) { asm volatile("s_waitcnt vmcnt(0)" ::: "memory"); }
        __builtin_amdgcn_s_barrier();
    }

    // ---- epilogue: C/D layout col=l16, row=quad*4+r (shape-determined)
    float sxv[8][4];
#pragma unroll
    for (int i = 0; i < 8; ++i)
#pragma unroll
        for (int r = 0; r < 4; ++r)
            sxv[i][r] = sx[tileM + wm * 128 + i * 16 + quad * 4 + r];

#pragma unroll
    for (int j = 0; j < 4; ++j) {
        const int n = tileN + wn * 64 + j * 16 + l16;
        const float scn = scale[n];
        const float bsn = bias[n];
#pragma unroll
        for (int i = 0; i < 8; ++i) {
            const size_t mrow = (size_t)(tileM + wm * 128 + i * 16 + quad * 4);
#pragma unroll
            for (int r = 0; r < 4; ++r)
                y[(mrow + r) * NDIM + n] = (float)acc[i][j][r] * sxv[i][r] * scn + bsn;
        }
    }
#undef STAGE_A
#undef STAGE_B
}

// ---------------------------------------------------------------------------
extern "C" void kernel_launch(void* const* d_in, const int* in_sizes, int n_in,
                              void* d_out, int out_size, void* d_ws, size_t ws_size,
                              hipStream_t stream) {
    const float* x      = (const float*)d_in[0];   // [4,2048,4096] f32
    const int*   wdat   = (const int*)d_in[1];     // [16384,4096] int32 (int8 range)
    const float* scale  = (const float*)d_in[2];   // [16384,1]
    const float* bias   = (const float*)d_in[3];   // [16384]
    float* y = (float*)d_out;                      // [4,2048,16384] f32

    signed char* wq = (signed char*)d_ws;                       // N*K   = 64 MiB
    signed char* xq = wq + (size_t)NDIM * KDIM;                 // M*K   = 32 MiB
    float*       sx = (float*)(xq + (size_t)MDIM * KDIM);       // M*4   = 32 KiB

    conv_w<<<(NDIM * (size_t)KDIM) / 4 / 256, 256, 0, stream>>>((const int4*)wdat,
                                                                (int*)wq);
    quant_rows<<<MDIM, 256, 0, stream>>>(x, (int*)xq, sx);

    dim3 grid(NDIM / BN, MDIM / BM);   // (64, 32) = 2048 blocks
    gemm_i8<<<grid, 512, 0, stream>>>(xq, wq, sx, scale, bias, y);
}

// Round 2
// 1341.911 us; speedup vs baseline: 1.1514x; 1.0251x over previous
//
#include <hip/hip_runtime.h>
#include <cstdint>

// Problem dims (fixed by reference): B=4, S=2048 -> M=8192, K=4096, N=16384
#define MDIM 8192
#define KDIM 4096
#define NDIM 16384

// GEMM geometry: 256x256 tile, 512 thr / 8 waves (2M x 4N), BK=64 bytes,
// 4-deep global_load_lds pipeline with counted vmcnt (T3+T4), T2 swizzle,
// T5 setprio, T1 XCD-chunked block swizzle.
// Round 2: STATIC LDS buffer indices (4x unrolled tile groups + peeled tail)
// so the compiler waitcnt pass can pair LDS-DMA writes with ds_reads and
// stop draining vmcnt(0) per phase (suspected round-1 pathology).
#define BM 256
#define BN 256
#define BKB 64              // K-bytes per tile step (1 mfma k-step)
#define NT (KDIM / BKB)     // 64 K-tiles
#define NBUF 4

typedef int v4i __attribute__((ext_vector_type(4)));

__device__ __forceinline__ void gload_lds16(const void* g, void* l) {
    __builtin_amdgcn_global_load_lds(
        (const __attribute__((address_space(1))) int*)g,
        (__attribute__((address_space(3))) int*)l, 16, 0, 0);
}

// ---------------------------------------------------------------------------
// Kernel 1: pack W int32 [N,K] -> int8 [N,K]. One int4 (4 ints) -> one int (4 bytes).
__global__ __launch_bounds__(256) void conv_w(const int4* __restrict__ w,
                                              int* __restrict__ wq) {
    int g = blockIdx.x * 256 + threadIdx.x;   // int4 index; total N*K/4 = 16777216
    int4 v = w[g];
    unsigned p = (unsigned)(v.x & 255) | ((unsigned)(v.y & 255) << 8) |
                 ((unsigned)(v.z & 255) << 16) | ((unsigned)(v.w & 255) << 24);
    wq[g] = (int)p;
}

// ---------------------------------------------------------------------------
// Kernel 2: per-row absmax quantize of x [M,K] fp32 -> int8 + scale_x[M].
__global__ __launch_bounds__(256) void quant_rows(const float* __restrict__ x,
                                                  int* __restrict__ xq32,
                                                  float* __restrict__ sx) {
    const int row = blockIdx.x;
    const int t = threadIdx.x;
    const float4* xr = (const float4*)(x + (size_t)row * KDIM);

    float4 v[4];
    float amax = 0.f;
#pragma unroll
    for (int p = 0; p < 4; ++p) {
        v[p] = xr[p * 256 + t];
        amax = fmaxf(amax, fmaxf(fmaxf(fabsf(v[p].x), fabsf(v[p].y)),
                                 fmaxf(fabsf(v[p].z), fabsf(v[p].w))));
    }
#pragma unroll
    for (int off = 32; off > 0; off >>= 1)
        amax = fmaxf(amax, __shfl_down(amax, off));
    __shared__ float wmax[4];
    int wave = t >> 6, lane = t & 63;
    if (lane == 0) wmax[wave] = amax;
    __syncthreads();
    float m = fmaxf(fmaxf(wmax[0], wmax[1]), fmaxf(wmax[2], wmax[3]));

    float inv = (m > 0.f) ? 127.f / m : 0.f;
    if (t == 0) {
        float s = m / 127.f;
        sx[row] = (s == 0.f) ? 1.f : s;
    }

    int* out = xq32 + (size_t)row * (KDIM / 4);
#pragma unroll
    for (int p = 0; p < 4; ++p) {
        int q0 = (int)rintf(v[p].x * inv); q0 = max(-127, min(127, q0));
        int q1 = (int)rintf(v[p].y * inv); q1 = max(-127, min(127, q1));
        int q2 = (int)rintf(v[p].z * inv); q2 = max(-127, min(127, q2));
        int q3 = (int)rintf(v[p].w * inv); q3 = max(-127, min(127, q3));
        unsigned pk = (unsigned)(q0 & 255) | ((unsigned)(q1 & 255) << 8) |
                      ((unsigned)(q2 & 255) << 16) | ((unsigned)(q3 & 255) << 24);
        out[p * 256 + t] = (int)pk;
    }
}

// ---------------------------------------------------------------------------
// Kernel 3: int8 GEMM 256x256 tile, phase schedule with static LDS dbuf indices.
__global__ __launch_bounds__(512, 2) void gemm_i8(const signed char* __restrict__ xq,
                                                  const signed char* __restrict__ wq,
                                                  const float* __restrict__ sx,
                                                  const float* __restrict__ scale,
                                                  const float* __restrict__ bias,
                                                  float* __restrict__ y) {
    // 4 buffers x (A 16KB + B 16KB) = 128 KiB LDS -> 1 block/CU, 2 waves/SIMD
    __shared__ __align__(16) signed char lds_a[NBUF][BM * BKB];
    __shared__ __align__(16) signed char lds_b[NBUF][BN * BKB];

    const int tid  = threadIdx.x;
    const int lane = tid & 63;
    const int wave = tid >> 6;           // 0..7
    const int l16  = lane & 15;
    const int quad = lane >> 4;
    const int wm   = wave >> 2;          // 0..1  M-half
    const int wn   = wave & 3;           // 0..3  N-quarter

    // T1: bijective XCD-chunked swizzle (2048 blocks, 2048 % 8 == 0)
    int lin = blockIdx.y * gridDim.x + blockIdx.x;
    lin = (lin & 7) * ((MDIM / BM) * (NDIM / BN) / 8) + (lin >> 3);
    const int tileN = (lin & (NDIM / BN - 1)) * BN;   // lin % 64
    const int tileM = (lin >> 6) * BM;                // lin / 64

    // ---- staging addressing. T2 swizzle: LDS stays LINEAR for global_load_lds;
    // the global SOURCE column is pre-swizzled with the same involution the
    // ds_read side applies (rule 21: both-sides-or-neither).
    const int srow = tid >> 2;                                   // 0..127
    const int scol = ((tid & 3) << 4) ^ (((srow >> 1) & 3) << 4);
    const signed char* gA0 = xq + (size_t)(tileM + srow) * KDIM + scol;
    const signed char* gA1 = gA0 + (size_t)128 * KDIM;           // rows 128..255
    const signed char* gB0 = wq + (size_t)(tileN + srow) * KDIM + scol;
    const signed char* gB1 = gB0 + (size_t)128 * KDIM;
    const int lo = tid << 4;             // linear LDS byte offset of this thread's chunk

    // ---- ds_read addressing with the same XOR swizzle.
    // row = 16*a + l16 -> ((row>>1)&3) == ((l16>>1)&3): per-lane constant.
    const int rcol = (quad << 4) ^ (((l16 >> 1) & 3) << 4);
    const int aoff = (wm * 128 + l16) * BKB + rcol;   // + mf*1024
    const int boff = (wn * 64 + l16) * BKB + rcol;    // + nf*1024

    v4i acc[8][4] = {};

// Stage tile (global byte offset GOFF) into STATIC buffer index BUF.
#define STAGE_A(GOFF, BUF) do {                                               \
        gload_lds16(gA0 + (GOFF), &lds_a[BUF][lo]);                           \
        gload_lds16(gA1 + (GOFF), &lds_a[BUF][lo + 8192]); } while (0)
#define STAGE_B(GOFF, BUF) do {                                               \
        gload_lds16(gB0 + (GOFF), &lds_b[BUF][lo]);                           \
        gload_lds16(gB1 + (GOFF), &lds_b[BUF][lo + 8192]); } while (0)

// One K-tile: reads STATIC buffer BC_; optionally prefetches tile at global
// byte offset PFOFF_ into static buffer (BC_+3)&3. Trailing vmcnt/barrier at
// the call site.
#define KTILE(BC_, DO_PF_, PFOFF_) do {                                       \
    v4i af_[4], bf_[4], ag_[4];                                               \
    _Pragma("unroll")                                                         \
    for (int i_ = 0; i_ < 4; ++i_)                                            \
        af_[i_] = *(const v4i*)(&lds_a[BC_][0] + aoff + i_ * 1024);           \
    _Pragma("unroll")                                                         \
    for (int j_ = 0; j_ < 4; ++j_)                                            \
        bf_[j_] = *(const v4i*)(&lds_b[BC_][0] + boff + j_ * 1024);           \
    if (DO_PF_) STAGE_A(PFOFF_, ((BC_) + 3) & 3);                             \
    __builtin_amdgcn_s_barrier();                                             \
    asm volatile("s_waitcnt lgkmcnt(0)" ::: "memory");                        \
    __builtin_amdgcn_sched_barrier(0);                                        \
    __builtin_amdgcn_s_setprio(1);                                            \
    _Pragma("unroll")                                                         \
    for (int i_ = 0; i_ < 4; ++i_)                                            \
        _Pragma("unroll")                                                     \
        for (int j_ = 0; j_ < 4; ++j_)                                        \
            acc[i_][j_] = __builtin_amdgcn_mfma_i32_16x16x64_i8(              \
                af_[i_], bf_[j_], acc[i_][j_], 0, 0, 0);                      \
    __builtin_amdgcn_s_setprio(0);                                            \
    __builtin_amdgcn_s_barrier();                                             \
    _Pragma("unroll")                                                         \
    for (int i_ = 0; i_ < 4; ++i_)                                            \
        ag_[i_] = *(const v4i*)(&lds_a[BC_][0] + aoff + (4 + i_) * 1024);     \
    if (DO_PF_) STAGE_B(PFOFF_, ((BC_) + 3) & 3);                             \
    __builtin_amdgcn_s_barrier();                                             \
    asm volatile("s_waitcnt lgkmcnt(0)" ::: "memory");                        \
    __builtin_amdgcn_sched_barrier(0);                                        \
    __builtin_amdgcn_s_setprio(1);                                            \
    _Pragma("unroll")                                                         \
    for (int i_ = 0; i_ < 4; ++i_)                                            \
        _Pragma("unroll")                                                     \
        for (int j_ = 0; j_ < 4; ++j_)                                        \
            acc[4 + i_][j_] = __builtin_amdgcn_mfma_i32_16x16x64_i8(          \
                ag_[i_], bf_[j_], acc[4 + i_][j_], 0, 0, 0);                  \
    __builtin_amdgcn_s_setprio(0);                                            \
} while (0)

#define VMW(N) asm volatile("s_waitcnt vmcnt(" #N ")" ::: "memory")

    // ---- prologue: tiles 0,1,2 in flight (12 loads); tile0 ready at vmcnt(8)
    STAGE_A((size_t)0 * BKB, 0); STAGE_B((size_t)0 * BKB, 0);
    STAGE_A((size_t)1 * BKB, 1); STAGE_B((size_t)1 * BKB, 1);
    STAGE_A((size_t)2 * BKB, 2); STAGE_B((size_t)2 * BKB, 2);
    VMW(8);
    __builtin_amdgcn_s_barrier();

    // ---- main loop: tiles 0..59 in groups of 4 (static buffer index = i),
    // every tile prefetches tile t+3. T4: counted vmcnt(8) once per K-tile.
    for (int g = 0; g < 15; ++g) {
        const size_t kb = (size_t)g * 4 * BKB;   // global byte offset of tile 4g
#pragma unroll
        for (int i = 0; i < 4; ++i) {
            KTILE(i, true, kb + (size_t)(i + 3) * BKB);
            VMW(8);
            __builtin_amdgcn_s_barrier();
        }
    }

    // ---- tail: tiles 60..63 (buffers 0..3); vmcnt countdown 8 -> 4 -> 0.
    KTILE(0, true, (size_t)63 * BKB);   // prefetch last tile 63 -> buf 3
    VMW(8);
    __builtin_amdgcn_s_barrier();
    KTILE(1, false, 0);
    VMW(4);
    __builtin_amdgcn_s_barrier();
    KTILE(2, false, 0);
    VMW(0);
    __builtin_amdgcn_s_barrier();
    KTILE(3, false, 0);                 // last tile: no trailing sync needed

    // ---- epilogue: C/D layout col=l16, row=quad*4+r (shape-determined)
    float sxv[8][4];
#pragma unroll
    for (int i = 0; i < 8; ++i)
#pragma unroll
        for (int r = 0; r < 4; ++r)
            sxv[i][r] = sx[tileM + wm * 128 + i * 16 + quad * 4 + r];

#pragma unroll
    for (int j = 0; j < 4; ++j) {
        const int n = tileN + wn * 64 + j * 16 + l16;
        const float scn = scale[n];
        const float bsn = bias[n];
#pragma unroll
        for (int i = 0; i < 8; ++i) {
            const size_t mrow = (size_t)(tileM + wm * 128 + i * 16 + quad * 4);
#pragma unroll
            for (int r = 0; r < 4; ++r)
                y[(mrow + r) * NDIM + n] = (float)acc[i][j][r] * sxv[i][r] * scn + bsn;
        }
    }
#undef STAGE_A
#undef STAGE_B
#undef KTILE
#undef VMW
}

// ---------------------------------------------------------------------------
extern "C" void kernel_launch(void* const* d_in, const int* in_sizes, int n_in,
                              void* d_out, int out_size, void* d_ws, size_t ws_size,
                              hipStream_t stream) {
    const float* x      = (const float*)d_in[0];   // [4,2048,4096] f32
    const int*   wdat   = (const int*)d_in[1];     // [16384,4096] int32 (int8 range)
    const float* scale  = (const float*)d_in[2];   // [16384,1]
    const float* bias   = (const float*)d_in[3];   // [16384]
    float* y = (float*)d_out;                      // [4,2048,16384] f32

    signed char* wq = (signed char*)d_ws;                       // N*K   = 64 MiB
    signed char* xq = wq + (size_t)NDIM * KDIM;                 // M*K   = 32 MiB
    float*       sx = (float*)(xq + (size_t)MDIM * KDIM);       // M*4   = 32 KiB

    conv_w<<<(NDIM * (size_t)KDIM) / 4 / 256, 256, 0, stream>>>((const int4*)wdat,
                                                                (int*)wq);
    quant_rows<<<MDIM, 256, 0, stream>>>(x, (int*)xq, sx);

    dim3 grid(NDIM / BN, MDIM / BM);   // (64, 32) = 2048 blocks
    gemm_i8<<<grid, 512, 0, stream>>>(xq, wq, sx, scale, bias, y);
}